// Round 19
// baseline (83.335 us; speedup 1.0000x reference)
//
#include <hip/hip_runtime.h>

#define POISON 0xAAAAAAAAu
#define NMLP 16u

// Exact (non-approximate) GELU, matching jax.nn.gelu(approximate=False).
__device__ __forceinline__ float gelu_exact(float x) {
    return 0.5f * x * (1.0f + erff(x * 0.7071067811865475f));
}

__device__ __forceinline__ float dot4(float4 a, float4 b) {
    return a.x * b.x + a.y * b.y + a.z * b.z + a.w * b.w;
}

// 16-block barrier, relaxed RMW polling (r16-proven; measured ~1-1.5us vs a
// ~3.3us kernel-boundary gap per r16/r17 algebra). Poll is a relaxed
// fetch_add(0): coherence-point read, NO per-poll cache invalidate (the
// acquire-poll invalidation storm was r9/r12's chip-crawl). One
// __threadfence() after exit = the single acquire-invalidate making
// post-barrier plain loads of coherence-point data fresh. Slot starts as
// harness 0xAA poison; every block CASes POISON->0 at kernel entry.
__device__ __forceinline__ void mlp_barrier(unsigned* slot) {
    __syncthreads();                      // drains this block's z3p exchanges
    if (threadIdx.x == 0) {
        atomicAdd(slot, 1u);
        while (__hip_atomic_fetch_add(slot, 0u, __ATOMIC_RELAXED,
                                      __HIP_MEMORY_SCOPE_AGENT) < NMLP)
            __builtin_amdgcn_s_sleep(16);
        __threadfence();                  // single acquire-invalidate
    }
    __syncthreads();
}

// F1 (16 blocks x 256): K-split MLP through L4, ONE in-kernel barrier.
//   Block m owns k-slice [m*16, m*16+16).
//   L1 redundant (4KB) -> L2 slice (16 neurons, 16-lane clubs) ->
//   L3 partials for ALL 256 neurons over the slice, stored via agent-scope
//   atomic EXCHANGE (coherence point => cross-XCD visible in-kernel;
//   r13/r16-proven) -> relaxed barrier -> merge 16 partials (fixed order,
//   deterministic) -> x3 slice -> L4 partials via PLAIN stores (read by K3
//   across the dispatch boundary; r17-proven).
// ws layout (floats): z3p = ws[0..4095], z4p = ws[4096..8191], bar = ws[8192].
__global__ __launch_bounds__(256) void f1_kernel(
    const float* __restrict__ W1, const float* __restrict__ b1,
    const float* __restrict__ W2, const float* __restrict__ b2,
    const float* __restrict__ W3, const float* __restrict__ b3,
    const float* __restrict__ W4, float* __restrict__ ws)
{
    float*    z3p = ws;                      // [16][256] via atomic exchange
    float*    z4p = ws + 4096;               // [16][256] plain stores
    unsigned* bar = (unsigned*)(ws + 8192);

    __shared__ __align__(16) float x1l[256];
    __shared__ __align__(16) float x2l[16];
    __shared__ float zred[256];
    __shared__ __align__(16) float x3l[16];

    const int t = threadIdx.x;
    const int m = blockIdx.x;                // k-slice 0..15
    const int q = t >> 4;                    // neuron-in-slice 0..15
    const int c = t & 15;                    // club lane 0..15

    if (t == 0) atomicCAS(bar, POISON, 0u);  // poison-init before any arrival

    // ---- Layer 1: MLP input is [0,0,1,1]; W1 [256,4] row-major ----
    {
        float4 w1r = *reinterpret_cast<const float4*>(W1 + t * 4);
        x1l[t] = gelu_exact(w1r.z + w1r.w + b1[t]);
    }
    __syncthreads();

    // ---- Layer 2, this block's 16 neurons ----
    {
        const int n = m * 16 + q;
        float acc = 0.f;
        #pragma unroll
        for (int i = 0; i < 4; ++i) {
            float4 wv = *reinterpret_cast<const float4*>(W2 + (size_t)n * 256 + c * 16 + i * 4);
            float4 xv = *reinterpret_cast<const float4*>(x1l + c * 16 + i * 4);
            acc += dot4(wv, xv);
        }
        #pragma unroll
        for (int off = 1; off <= 8; off <<= 1) acc += __shfl_xor(acc, off);
        if (c == 0) x2l[q] = gelu_exact(acc + b2[n]);
    }
    __syncthreads();

    // ---- L3 partials: thread t -> neuron t, k in [m*16, m*16+16) ----
    {
        float a3 = 0.f;
        #pragma unroll
        for (int i = 0; i < 4; ++i) {
            float4 wv = *reinterpret_cast<const float4*>(W3 + (size_t)t * 256 + m * 16 + i * 4);
            float4 xv = *reinterpret_cast<const float4*>(x2l + i * 4);
            a3 += dot4(wv, xv);
        }
        __hip_atomic_exchange(&z3p[m * 256 + t], a3,
                              __ATOMIC_RELEASE, __HIP_MEMORY_SCOPE_AGENT);
    }
    mlp_barrier(bar);

    // ---- Merge z3 slice (fixed jj order) -> x3 slice ----
    zred[t] = z3p[(t >> 4) * 256 + m * 16 + (t & 15)];   // plain, post-fence
    __syncthreads();
    if (t < 16) {
        float s = 0.f;
        #pragma unroll
        for (int jj = 0; jj < 16; ++jj) s += zred[jj * 16 + t];
        x3l[t] = gelu_exact(s + b3[m * 16 + t]);
    }
    __syncthreads();

    // ---- L4 partials: plain stores (dispatch boundary syncs for K3) ----
    {
        float a4 = 0.f;
        #pragma unroll
        for (int i = 0; i < 4; ++i) {
            float4 wv = *reinterpret_cast<const float4*>(W4 + (size_t)t * 256 + m * 16 + i * 4);
            float4 xv = *reinterpret_cast<const float4*>(x3l + i * 4);
            a4 += dot4(wv, xv);
        }
        z4p[m * 256 + t] = a4;
    }
}

// K3 (256 blocks x 256): merge z4 -> x4 -> w12 (redundant, 12KB W5) -> apply.
// pred[b,p,d] = sum_c feat[b,c,p] * w12[c*3+d].  (unchanged from r17)
__global__ __launch_bounds__(256) void k3_kernel(
    const float* __restrict__ b4, const float* __restrict__ W5,
    const float* __restrict__ b5, const float* __restrict__ feat,
    float* __restrict__ out, const float* __restrict__ ws)
{
    const float* z4p = ws + 4096;
    __shared__ __align__(16) float x4l[256];
    __shared__ float wl[12];

    const int t = threadIdx.x;

    // Apply-slice addresses; issue feat loads FIRST (latency overlaps merge).
    const int idx = blockIdx.x * 256 + t;    // 0..65535 quad index
    const int b   = idx >> 14;
    const int pos = (idx & 16383) << 2;
    const float* fb = feat + (size_t)b * 4 * 65536 + pos;
    const float4 f0 = *reinterpret_cast<const float4*>(fb);
    const float4 f1 = *reinterpret_cast<const float4*>(fb + 65536);
    const float4 f2 = *reinterpret_cast<const float4*>(fb + 131072);
    const float4 f3 = *reinterpret_cast<const float4*>(fb + 196608);

    // Merge z4 (fixed order) + gelu -> x4.
    {
        float s = b4[t];
        #pragma unroll
        for (int j = 0; j < 16; ++j) s += z4p[j * 256 + t];  // coalesced per j
        x4l[t] = gelu_exact(s);
    }
    __syncthreads();

    // w12 = W5 @ x4 + b5 (12 outputs; club of 16 per output, shfl reduce).
    {
        const int q = t >> 4;                // 0..15 (12 used)
        const int c = t & 15;
        if (q < 12) {
            float acc = 0.f;
            #pragma unroll
            for (int i = 0; i < 4; ++i) {
                float4 wv = *reinterpret_cast<const float4*>(W5 + (size_t)q * 256 + c * 16 + i * 4);
                float4 xv = *reinterpret_cast<const float4*>(x4l + c * 16 + i * 4);
                acc += dot4(wv, xv);
            }
            #pragma unroll
            for (int off = 1; off <= 8; off <<= 1) acc += __shfl_xor(acc, off);
            if (c == 0) wl[q] = acc + b5[q];
        }
    }
    __syncthreads();

    float wr[12];
    #pragma unroll
    for (int i = 0; i < 12; ++i) wr[i] = wl[i];

    float r[12];
    #pragma unroll
    for (int dd = 0; dd < 3; ++dd) {
        r[0 + dd] = f0.x * wr[dd] + f1.x * wr[3 + dd] + f2.x * wr[6 + dd] + f3.x * wr[9 + dd];
        r[3 + dd] = f0.y * wr[dd] + f1.y * wr[3 + dd] + f2.y * wr[6 + dd] + f3.y * wr[9 + dd];
        r[6 + dd] = f0.z * wr[dd] + f1.z * wr[3 + dd] + f2.z * wr[6 + dd] + f3.z * wr[9 + dd];
        r[9 + dd] = f0.w * wr[dd] + f1.w * wr[3 + dd] + f2.w * wr[6 + dd] + f3.w * wr[9 + dd];
    }

    float* op = out + (size_t)(b * 65536 + pos) * 3;
    reinterpret_cast<float4*>(op)[0] = make_float4(r[0], r[1], r[2],  r[3]);
    reinterpret_cast<float4*>(op)[1] = make_float4(r[4], r[5], r[6],  r[7]);
    reinterpret_cast<float4*>(op)[2] = make_float4(r[8], r[9], r[10], r[11]);
}

extern "C" void kernel_launch(void* const* d_in, const int* in_sizes, int n_in,
                              void* d_out, int out_size, void* d_ws, size_t ws_size,
                              hipStream_t stream) {
    const float* feat = (const float*)d_in[0];
    const float* W1   = (const float*)d_in[1];
    const float* b1   = (const float*)d_in[2];
    const float* W2   = (const float*)d_in[3];
    const float* b2   = (const float*)d_in[4];
    const float* W3   = (const float*)d_in[5];
    const float* b3   = (const float*)d_in[6];
    const float* W4   = (const float*)d_in[7];
    const float* b4   = (const float*)d_in[8];
    const float* W5   = (const float*)d_in[9];
    const float* b5   = (const float*)d_in[10];

    float* out = (float*)d_out;   // [4, 65536, 3] fp32
    float* ws  = (float*)d_ws;

    f1_kernel<<<16, 256, 0, stream>>>(W1, b1, W2, b2, W3, b3, W4, ws);
    k3_kernel<<<256, 256, 0, stream>>>(b4, W5, b5, feat, out, ws);
}